// Round 1
// baseline (77.095 us; speedup 1.0000x reference)
//
#include <hip/hip_runtime.h>
#include <math.h>

#define S 256
#define H 1024
#define NTAG 20
#define NPAIR 32640  // S*(S-1)/2

// ---- workspace layout (float indices) ----
#define WS_APART 0       // [16][256] partial a sums per col-tile
#define WS_E     4096    // [256]
#define WS_ZC    4352    // [257]
#define WS_HW0   4640    // [256*20]
#define WS_HW1   9760    // [256*20]
#define WS_HW2   14880   // [256*20]
#define WS_PW    20000   // [257*20]
#define WS_LW    25140   // [257*20] indexed by L=j-i+1 in [2,256]
#define WS_LOSSP 30280   // [255]
#define WS_RUN   30535   // int[256]
#define WS_START 30791   // int[256]
#define WS_END   31047   // int[256]
// total ~31303 floats = ~125 KB

// Kernel A: a_part[ct][s] = sum over 64-col tile of tanh(hidden@w1 + b1) * w2
// grid (16 col-tiles, 16 row-tiles), 256 threads. BM=16 rows, BN=64 cols, BK=32.
__global__ __launch_bounds__(256) void kA(const float* __restrict__ hidden,
                                          const float* __restrict__ w1,
                                          const float* __restrict__ b1,
                                          const float* __restrict__ w2,
                                          float* __restrict__ ws) {
    const int tid = threadIdx.x;
    const int c0 = blockIdx.x * 64;
    const int r0 = blockIdx.y * 16;

    __shared__ __align__(16) float shT[32][20];  // [kk][row], padded stride 20
    __shared__ float shW[32][64];                // [kk][col]
    __shared__ float sred[16][65];

    const int c  = tid & 63;
    const int rq = tid >> 6;           // 0..3 -> rows rq*4..rq*4+3
    const int h_lr = tid >> 4;         // 0..15
    const int h_kk = (tid & 15) * 2;   // 0..30
    const int w_lc = tid & 63;
    const int w_k0 = (tid >> 6) * 8;

    float acc0 = 0.f, acc1 = 0.f, acc2 = 0.f, acc3 = 0.f;

    for (int k0 = 0; k0 < H; k0 += 32) {
        float2 hv = *(const float2*)&hidden[(r0 + h_lr) * H + k0 + h_kk];
        shT[h_kk][h_lr]     = hv.x;
        shT[h_kk + 1][h_lr] = hv.y;
        #pragma unroll
        for (int e = 0; e < 8; e++)
            shW[w_k0 + e][w_lc] = w1[(k0 + w_k0 + e) * H + c0 + w_lc];
        __syncthreads();
        #pragma unroll
        for (int kk = 0; kk < 32; kk++) {
            float4 h4 = *(const float4*)&shT[kk][rq * 4];
            float wv = shW[kk][c];
            acc0 = fmaf(h4.x, wv, acc0);
            acc1 = fmaf(h4.y, wv, acc1);
            acc2 = fmaf(h4.z, wv, acc2);
            acc3 = fmaf(h4.w, wv, acc3);
        }
        __syncthreads();
    }

    const float b1v = b1[c0 + c];
    const float w2v = w2[c0 + c];
    sred[rq * 4 + 0][c] = tanhf(acc0 + b1v) * w2v;
    sred[rq * 4 + 1][c] = tanhf(acc1 + b1v) * w2v;
    sred[rq * 4 + 2][c] = tanhf(acc2 + b1v) * w2v;
    sred[rq * 4 + 3][c] = tanhf(acc3 + b1v) * w2v;
    __syncthreads();
    if (tid < 16) {
        float ssum = 0.f;
        for (int cc = 0; cc < 64; cc++) ssum += sred[tid][cc];
        ws[WS_APART + blockIdx.x * 256 + r0 + tid] = ssum;
    }
}

// Kernel B: finalize scores a, compute e=exp(a-max), Zc cumsum, run-id/start/end
__global__ __launch_bounds__(256) void kB(const float* __restrict__ b2,
                                          const int* __restrict__ target,
                                          float* __restrict__ ws) {
    const int s = threadIdx.x;
    __shared__ float sh[256];
    __shared__ float she[256];
    __shared__ int shtg[256];

    float a = b2[0];
    #pragma unroll
    for (int ct = 0; ct < 16; ct++) a += ws[WS_APART + ct * 256 + s];
    sh[s] = a;
    shtg[s] = target[s];
    __syncthreads();
    for (int off = 128; off > 0; off >>= 1) {
        if (s < off) sh[s] = fmaxf(sh[s], sh[s + off]);
        __syncthreads();
    }
    const float mx = sh[0];
    const float ev = expf(a - mx);
    she[s] = ev;
    ws[WS_E + s] = ev;
    const int st = (s == 0)   ? 1 : (shtg[s] != shtg[s - 1]);
    const int en = (s == 255) ? 1 : (shtg[s] != shtg[s + 1]);
    ((int*)ws)[WS_START + s] = st;
    ((int*)ws)[WS_END + s]   = en;
    __syncthreads();
    if (s == 0) {
        float z = 0.f;
        ws[WS_ZC + 0] = 0.f;
        for (int t = 0; t < 256; t++) { z += she[t]; ws[WS_ZC + t + 1] = z; }
        int rid = 0;
        for (int t = 0; t < 256; t++) {
            rid += (t == 0) ? 1 : (shtg[t] != shtg[t - 1]);
            ((int*)ws)[WS_RUN + t] = rid;
        }
    }
}

// Kernel C: blocks 0..255 -> hw0/hw1/hw2[s][t] = hidden[s,:] @ fc_w[p*H:(p+1)*H, t]
//           block 256 -> lw[L][t] = len_emb[L,:] @ fc_w[3072:3082, t]
__global__ __launch_bounds__(256) void kC(const float* __restrict__ hidden,
                                          const float* __restrict__ fcw,
                                          const float* __restrict__ lenemb,
                                          float* __restrict__ ws) {
    const int b = blockIdx.x;
    const int tid = threadIdx.x;
    if (b < 256) {
        __shared__ float hrow[1024];
        __shared__ float part[12][20];
        #pragma unroll
        for (int e = 0; e < 4; e++) hrow[tid + e * 256] = hidden[b * H + tid + e * 256];
        __syncthreads();
        if (tid < 240) {
            const int t = tid % 20, g = tid / 20;      // g 0..11
            const int p = g >> 2, kc = g & 3;          // p 0..2, kc 0..3
            const float* fw = fcw + ((p << 10) + (kc << 8)) * 20 + t;
            const float* hr = hrow + (kc << 8);
            float sacc = 0.f;
            #pragma unroll 8
            for (int k = 0; k < 256; k++) sacc = fmaf(hr[k], fw[k * 20], sacc);
            part[g][t] = sacc;
        }
        __syncthreads();
        if (tid < 60) {
            const int t = tid % 20, p = tid / 20;
            float v = part[p * 4 + 0][t] + part[p * 4 + 1][t] +
                      part[p * 4 + 2][t] + part[p * 4 + 3][t];
            const int base = (p == 0) ? WS_HW0 : (p == 1) ? WS_HW1 : WS_HW2;
            ws[base + b * 20 + t] = v;
        }
    } else {
        for (int item = tid; item < 255 * 20; item += 256) {
            const int L = 2 + item / 20;
            const int t = item % 20;
            float v = 0.f;
            #pragma unroll
            for (int d = 0; d < 10; d++)
                v = fmaf(lenemb[L * 10 + d], fcw[(3072 + d) * 20 + t], v);
            ws[WS_LW + L * 20 + t] = v;
        }
    }
}

// Kernel D: Pw[s+1][t] = cumsum_s e[s]*hw0[s][t]
__global__ __launch_bounds__(64) void kD(float* __restrict__ ws) {
    __shared__ float she[256];
    const int tid = threadIdx.x;
    for (int e = tid; e < 256; e += 64) she[e] = ws[WS_E + e];
    __syncthreads();
    if (tid < 20) {
        float pw = 0.f;
        ws[WS_PW + tid] = 0.f;
        #pragma unroll 4
        for (int s2 = 0; s2 < 256; s2++) {
            pw = fmaf(she[s2], ws[WS_HW0 + s2 * 20 + tid], pw);
            ws[WS_PW + (s2 + 1) * 20 + tid] = pw;
        }
    }
}

// Kernel E: per-pair logits + log-softmax loss partials. block i=0..254, thread j.
__global__ __launch_bounds__(256) void kE(const int* __restrict__ target,
                                          const float* __restrict__ fcb,
                                          float* __restrict__ out,
                                          float* __restrict__ ws) {
    const int i = blockIdx.x;
    const int j = threadIdx.x;
    __shared__ float sPwi[20], shw1i[20], sfcb[20];
    __shared__ float sred[256];

    if (j < 20) {
        sPwi[j]  = ws[WS_PW + i * 20 + j];
        shw1i[j] = ws[WS_HW1 + i * 20 + j];
        sfcb[j]  = fcb[j];
    }
    __syncthreads();

    const int* runid = (const int*)ws + WS_RUN;
    const int* stA   = (const int*)ws + WS_START;
    const int* enA   = (const int*)ws + WS_END;

    float lossacc = 0.f;
    if (j > i) {
        const float Zci  = ws[WS_ZC + i];
        const float invz = 1.f / (ws[WS_ZC + j + 1] - Zci);
        const int L = j - i + 1;
        const int lbl = (runid[i] == runid[j] && stA[i] && enA[j]) ? target[j] : 0;

        // vectorized table loads into register arrays (static indices only)
        float pwv[20], h2v[20], lwv[20];
        const float4* pw4 = (const float4*)(ws + WS_PW + (j + 1) * 20);
        const float4* h24 = (const float4*)(ws + WS_HW2 + j * 20);
        const float4* lw4 = (const float4*)(ws + WS_LW + L * 20);
        #pragma unroll
        for (int q = 0; q < 5; q++) {
            float4 a = pw4[q], b = h24[q], cc = lw4[q];
            pwv[q*4+0]=a.x; pwv[q*4+1]=a.y; pwv[q*4+2]=a.z; pwv[q*4+3]=a.w;
            h2v[q*4+0]=b.x; h2v[q*4+1]=b.y; h2v[q*4+2]=b.z; h2v[q*4+3]=b.w;
            lwv[q*4+0]=cc.x; lwv[q*4+1]=cc.y; lwv[q*4+2]=cc.z; lwv[q*4+3]=cc.w;
        }

        float lg[20];
        float mx = -1e30f, chosen = 0.f;
        #pragma unroll
        for (int t = 0; t < 20; t++) {
            float v = (pwv[t] - sPwi[t]) * invz + shw1i[t] + h2v[t] + lwv[t] + sfcb[t];
            lg[t] = v;
            mx = fmaxf(mx, v);
            chosen = (t == lbl) ? v : chosen;
        }
        const int p = i * 255 - (i * (i - 1)) / 2 + (j - i - 1);
        float4* op4 = (float4*)(out + (size_t)p * 20);
        #pragma unroll
        for (int q = 0; q < 5; q++)
            op4[q] = make_float4(lg[q*4+0], lg[q*4+1], lg[q*4+2], lg[q*4+3]);

        float se = 0.f;
        #pragma unroll
        for (int t = 0; t < 20; t++) se += expf(lg[t] - mx);
        lossacc = -(chosen - mx - logf(se));
    }
    sred[j] = lossacc;
    __syncthreads();
    for (int off = 128; off > 0; off >>= 1) {
        if (j < off) sred[j] += sred[j + off];
        __syncthreads();
    }
    if (j == 0) ws[WS_LOSSP + i] = sred[0];
}

// Kernel F: final loss reduction
__global__ __launch_bounds__(256) void kF(float* __restrict__ out,
                                          float* __restrict__ ws) {
    __shared__ float sh[256];
    const int t = threadIdx.x;
    sh[t] = (t < 255) ? ws[WS_LOSSP + t] : 0.f;
    __syncthreads();
    for (int off = 128; off > 0; off >>= 1) {
        if (t < off) sh[t] += sh[t + off];
        __syncthreads();
    }
    if (t == 0) out[(size_t)NPAIR * 20] = sh[0] / (float)NPAIR;
}

extern "C" void kernel_launch(void* const* d_in, const int* in_sizes, int n_in,
                              void* d_out, int out_size, void* d_ws, size_t ws_size,
                              hipStream_t stream) {
    (void)in_sizes; (void)n_in; (void)out_size; (void)ws_size;
    const float* hidden = (const float*)d_in[0];
    const int*   target = (const int*)d_in[1];
    const float* w1     = (const float*)d_in[2];
    const float* b1     = (const float*)d_in[3];
    const float* w2     = (const float*)d_in[4];
    const float* b2     = (const float*)d_in[5];
    const float* lenemb = (const float*)d_in[6];
    const float* fcw    = (const float*)d_in[7];
    const float* fcb    = (const float*)d_in[8];
    float* out = (float*)d_out;
    float* ws  = (float*)d_ws;

    kA<<<dim3(16, 16), 256, 0, stream>>>(hidden, w1, b1, w2, ws);
    kB<<<1, 256, 0, stream>>>(b2, target, ws);
    kC<<<257, 256, 0, stream>>>(hidden, fcw, lenemb, ws);
    kD<<<1, 64, 0, stream>>>(ws);
    kE<<<255, 256, 0, stream>>>(target, fcb, out, ws);
    kF<<<1, 256, 0, stream>>>(out, ws);
}

// Round 2
// 44.339 us; speedup vs baseline: 1.7388x; 1.7388x over previous
//
#include <hip/hip_runtime.h>
#include <math.h>

#define S 256
#define H 1024
#define NTAG 20
#define NPAIR 32640  // S*(S-1)/2

// ---- workspace layout (float indices) ----
#define WS_T     0          // [8 kc][256 s][1024 c] fp32 partial dots = 8 MB
#define WS_A     2097152    // [256] raw scores (pre-b2)
#define WS_E     2097408    // [256]
#define WS_ZC    2097664    // [257]
#define WS_HW0   2097924    // [256*20]  (16B-aligned)
#define WS_HW1   2103044    // [256*20]
#define WS_HW2   2108164    // [256*20]
#define WS_PW    2113284    // [257*20]
#define WS_LW    2118424    // [257*20] indexed by L=j-i+1 in [2,256]
#define WS_LOSSP 2123564    // [255]
#define WS_RUN   2123820    // int[256]
#define WS_START 2124076    // int[256]
#define WS_END   2124332    // int[256]
// total ~2124588 floats = ~8.5 MB

// Kernel A1: partial[kc][s][c] = sum over 128-K chunk of hidden[s][k]*w1[k][c]
// grid (4 colgroups, 16 rowgroups, 8 kchunks) = 512 blocks, 256 threads.
// Each thread: 16 row-accumulators for one column; w1 read coalesced from
// L2/L3; hidden chunk staged transposed in LDS, read as uniform broadcasts.
__global__ __launch_bounds__(256) void kA1(const float* __restrict__ hidden,
                                           const float* __restrict__ w1,
                                           float* __restrict__ ws) {
    const int tid = threadIdx.x;
    const int cg = blockIdx.x;   // 0..3   -> cols cg*256 + tid
    const int rg = blockIdx.y;   // 0..15  -> rows rg*16 .. +15
    const int kc = blockIdx.z;   // 0..7   -> k in kc*128 .. +127

    __shared__ __align__(16) float shH[128][16];  // [k][row]

    const int kk = tid & 127;
    const int r0 = (tid >> 7) * 8;
    #pragma unroll
    for (int e = 0; e < 8; e++)
        shH[kk][r0 + e] = hidden[(rg * 16 + r0 + e) * H + kc * 128 + kk];
    __syncthreads();

    float acc[16];
    #pragma unroll
    for (int r = 0; r < 16; r++) acc[r] = 0.f;

    const float* wp = w1 + (size_t)(kc * 128) * H + cg * 256 + tid;
    #pragma unroll 4
    for (int k = 0; k < 128; k++) {
        const float wv = wp[k * H];
        const float4 h0 = *(const float4*)&shH[k][0];
        const float4 h1 = *(const float4*)&shH[k][4];
        const float4 h2 = *(const float4*)&shH[k][8];
        const float4 h3 = *(const float4*)&shH[k][12];
        acc[0]  = fmaf(h0.x, wv, acc[0]);  acc[1]  = fmaf(h0.y, wv, acc[1]);
        acc[2]  = fmaf(h0.z, wv, acc[2]);  acc[3]  = fmaf(h0.w, wv, acc[3]);
        acc[4]  = fmaf(h1.x, wv, acc[4]);  acc[5]  = fmaf(h1.y, wv, acc[5]);
        acc[6]  = fmaf(h1.z, wv, acc[6]);  acc[7]  = fmaf(h1.w, wv, acc[7]);
        acc[8]  = fmaf(h2.x, wv, acc[8]);  acc[9]  = fmaf(h2.y, wv, acc[9]);
        acc[10] = fmaf(h2.z, wv, acc[10]); acc[11] = fmaf(h2.w, wv, acc[11]);
        acc[12] = fmaf(h3.x, wv, acc[12]); acc[13] = fmaf(h3.y, wv, acc[13]);
        acc[14] = fmaf(h3.z, wv, acc[14]); acc[15] = fmaf(h3.w, wv, acc[15]);
    }

    float* op = ws + WS_T + kc * (S * H) + (rg * 16) * H + cg * 256 + tid;
    #pragma unroll
    for (int r = 0; r < 16; r++) op[r * H] = acc[r];
}

// Kernel A2C: blocks 0..255 (one per row s):
//   part 1: a[s] = sum_c tanh(sum_kc partial[kc][s][c] + b1[c]) * w2[c]
//   part 2: hw0/hw1/hw2[s][t] projections (reuses staged hidden row)
// block 256: lw[L][t] table.
__global__ __launch_bounds__(256) void kA2C(const float* __restrict__ hidden,
                                            const float* __restrict__ b1,
                                            const float* __restrict__ w2,
                                            const float* __restrict__ fcw,
                                            const float* __restrict__ lenemb,
                                            float* __restrict__ ws) {
    const int b = blockIdx.x;
    const int tid = threadIdx.x;
    if (b < 256) {
        __shared__ float hrow[1024];
        __shared__ float part[12][20];
        __shared__ float sred[256];

        #pragma unroll
        for (int e = 0; e < 4; e++)
            hrow[tid + e * 256] = hidden[b * H + tid + e * 256];

        // part 1: reduce partial slabs -> tanh -> dot with w2
        float lacc = 0.f;
        #pragma unroll
        for (int q = 0; q < 4; q++) {
            const int c = q * 256 + tid;
            float sum = 0.f;
            #pragma unroll
            for (int kcz = 0; kcz < 8; kcz++)
                sum += ws[WS_T + kcz * (S * H) + b * H + c];
            lacc += tanhf(sum + b1[c]) * w2[c];
        }
        sred[tid] = lacc;
        __syncthreads();
        for (int off = 128; off > 0; off >>= 1) {
            if (tid < off) sred[tid] += sred[tid + off];
            __syncthreads();
        }
        if (tid == 0) ws[WS_A + b] = sred[0];

        // part 2: hw projections (hrow visible since first __syncthreads)
        if (tid < 240) {
            const int t = tid % 20, g = tid / 20;      // g 0..11
            const int p = g >> 2, kc = g & 3;          // p 0..2, kc 0..3
            const float* fw = fcw + ((p << 10) + (kc << 8)) * 20 + t;
            const float* hr = hrow + (kc << 8);
            float sacc = 0.f;
            #pragma unroll 8
            for (int k = 0; k < 256; k++) sacc = fmaf(hr[k], fw[k * 20], sacc);
            part[g][t] = sacc;
        }
        __syncthreads();
        if (tid < 60) {
            const int t = tid % 20, p = tid / 20;
            const float v = part[p * 4 + 0][t] + part[p * 4 + 1][t] +
                            part[p * 4 + 2][t] + part[p * 4 + 3][t];
            const int base = (p == 0) ? WS_HW0 : (p == 1) ? WS_HW1 : WS_HW2;
            ws[base + b * 20 + t] = v;
        }
    } else {
        for (int item = tid; item < 255 * 20; item += 256) {
            const int L = 2 + item / 20;
            const int t = item % 20;
            float v = 0.f;
            #pragma unroll
            for (int d = 0; d < 10; d++)
                v = fmaf(lenemb[L * 10 + d], fcw[(3072 + d) * 20 + t], v);
            ws[WS_LW + L * 20 + t] = v;
        }
    }
}

// Kernel BD: scores -> max -> e -> Zc scan; run-id scan; start/end; Pw cumsum.
__global__ __launch_bounds__(256) void kBD(const float* __restrict__ b2,
                                           const int* __restrict__ target,
                                           float* __restrict__ ws) {
    const int s = threadIdx.x;
    __shared__ float shf[256];
    __shared__ float she[256];
    __shared__ int   shi[256];
    __shared__ int   shtg[256];
    __shared__ float shw0[5120];

    shtg[s] = target[s];
    const float a = ws[WS_A + s] + b2[0];
    shf[s] = a;
    __syncthreads();
    for (int off = 128; off > 0; off >>= 1) {
        if (s < off) shf[s] = fmaxf(shf[s], shf[s + off]);
        __syncthreads();
    }
    const float mx = shf[0];
    __syncthreads();
    const float ev = expf(a - mx);
    she[s] = ev;
    ws[WS_E + s] = ev;
    shf[s] = ev;
    const int chg = (s == 0) ? 1 : (shtg[s] != shtg[s - 1]);
    shi[s] = chg;
    __syncthreads();
    // Hillis-Steele inclusive scans (float e, int change)
    for (int off = 1; off < 256; off <<= 1) {
        const float fv = (s >= off) ? shf[s - off] : 0.f;
        const int   iv = (s >= off) ? shi[s - off] : 0;
        __syncthreads();
        shf[s] += fv;
        shi[s] += iv;
        __syncthreads();
    }
    ws[WS_ZC + s + 1] = shf[s];
    if (s == 0) ws[WS_ZC] = 0.f;
    ((int*)ws)[WS_RUN + s]   = shi[s];
    ((int*)ws)[WS_START + s] = chg;
    ((int*)ws)[WS_END + s]   = (s == 255) ? 1 : (shtg[s] != shtg[s + 1]);
    // stage hw0 then Pw cumsum from LDS
    for (int idx = s; idx < 5120; idx += 256) shw0[idx] = ws[WS_HW0 + idx];
    __syncthreads();
    if (s < 20) {
        float pw = 0.f;
        ws[WS_PW + s] = 0.f;
        for (int s2 = 0; s2 < 256; s2++) {
            pw = fmaf(she[s2], shw0[s2 * 20 + s], pw);
            ws[WS_PW + (s2 + 1) * 20 + s] = pw;
        }
    }
}

// Kernel E: per-pair logits + log-softmax loss partials. block i=0..254, thread j.
__global__ __launch_bounds__(256) void kE(const int* __restrict__ target,
                                          const float* __restrict__ fcb,
                                          float* __restrict__ out,
                                          float* __restrict__ ws) {
    const int i = blockIdx.x;
    const int j = threadIdx.x;
    __shared__ float sPwi[20], shw1i[20], sfcb[20];
    __shared__ float sred[256];

    if (j < 20) {
        sPwi[j]  = ws[WS_PW + i * 20 + j];
        shw1i[j] = ws[WS_HW1 + i * 20 + j];
        sfcb[j]  = fcb[j];
    }
    __syncthreads();

    const int* runid = (const int*)ws + WS_RUN;
    const int* stA   = (const int*)ws + WS_START;
    const int* enA   = (const int*)ws + WS_END;

    float lossacc = 0.f;
    if (j > i) {
        const float Zci  = ws[WS_ZC + i];
        const float invz = 1.f / (ws[WS_ZC + j + 1] - Zci);
        const int L = j - i + 1;
        const int lbl = (runid[i] == runid[j] && stA[i] && enA[j]) ? target[j] : 0;

        float pwv[20], h2v[20], lwv[20];
        const float4* pw4 = (const float4*)(ws + WS_PW + (j + 1) * 20);
        const float4* h24 = (const float4*)(ws + WS_HW2 + j * 20);
        const float4* lw4 = (const float4*)(ws + WS_LW + L * 20);
        #pragma unroll
        for (int q = 0; q < 5; q++) {
            float4 a = pw4[q], b = h24[q], cc = lw4[q];
            pwv[q*4+0]=a.x; pwv[q*4+1]=a.y; pwv[q*4+2]=a.z; pwv[q*4+3]=a.w;
            h2v[q*4+0]=b.x; h2v[q*4+1]=b.y; h2v[q*4+2]=b.z; h2v[q*4+3]=b.w;
            lwv[q*4+0]=cc.x; lwv[q*4+1]=cc.y; lwv[q*4+2]=cc.z; lwv[q*4+3]=cc.w;
        }

        float lg[20];
        float mx = -1e30f, chosen = 0.f;
        #pragma unroll
        for (int t = 0; t < 20; t++) {
            const float v = (pwv[t] - sPwi[t]) * invz + shw1i[t] + h2v[t] + lwv[t] + sfcb[t];
            lg[t] = v;
            mx = fmaxf(mx, v);
            chosen = (t == lbl) ? v : chosen;
        }
        const int p = i * 255 - (i * (i - 1)) / 2 + (j - i - 1);
        float4* op4 = (float4*)(out + (size_t)p * 20);
        #pragma unroll
        for (int q = 0; q < 5; q++)
            op4[q] = make_float4(lg[q*4+0], lg[q*4+1], lg[q*4+2], lg[q*4+3]);

        float se = 0.f;
        #pragma unroll
        for (int t = 0; t < 20; t++) se += expf(lg[t] - mx);
        lossacc = -(chosen - mx - logf(se));
    }
    sred[j] = lossacc;
    __syncthreads();
    for (int off = 128; off > 0; off >>= 1) {
        if (j < off) sred[j] += sred[j + off];
        __syncthreads();
    }
    if (j == 0) ws[WS_LOSSP + i] = sred[0];
}

// Kernel F: final loss reduction
__global__ __launch_bounds__(256) void kF(float* __restrict__ out,
                                          float* __restrict__ ws) {
    __shared__ float sh[256];
    const int t = threadIdx.x;
    sh[t] = (t < 255) ? ws[WS_LOSSP + t] : 0.f;
    __syncthreads();
    for (int off = 128; off > 0; off >>= 1) {
        if (t < off) sh[t] += sh[t + off];
        __syncthreads();
    }
    if (t == 0) out[(size_t)NPAIR * 20] = sh[0] / (float)NPAIR;
}

extern "C" void kernel_launch(void* const* d_in, const int* in_sizes, int n_in,
                              void* d_out, int out_size, void* d_ws, size_t ws_size,
                              hipStream_t stream) {
    (void)in_sizes; (void)n_in; (void)out_size; (void)ws_size;
    const float* hidden = (const float*)d_in[0];
    const int*   target = (const int*)d_in[1];
    const float* w1     = (const float*)d_in[2];
    const float* b1     = (const float*)d_in[3];
    const float* w2     = (const float*)d_in[4];
    const float* b2     = (const float*)d_in[5];
    const float* lenemb = (const float*)d_in[6];
    const float* fcw    = (const float*)d_in[7];
    const float* fcb    = (const float*)d_in[8];
    float* out = (float*)d_out;
    float* ws  = (float*)d_ws;

    kA1<<<dim3(4, 16, 8), 256, 0, stream>>>(hidden, w1, ws);
    kA2C<<<257, 256, 0, stream>>>(hidden, b1, w2, fcw, lenemb, ws);
    kBD<<<1, 256, 0, stream>>>(b2, target, ws);
    kE<<<255, 256, 0, stream>>>(target, fcb, out, ws);
    kF<<<1, 256, 0, stream>>>(out, ws);
}